// Round 15
// baseline (430.390 us; speedup 1.0000x reference)
//
#include <hip/hip_runtime.h>
#include <math.h>

#define T_STEPS 1024
#define FORECAST 30

typedef __attribute__((ext_vector_type(8))) _Float16 half8;    // 8 fp16 = 4 VGPRs
typedef __attribute__((ext_vector_type(4))) float f32x4;

__device__ __forceinline__ float rcp_fast(float v){ return __builtin_amdgcn_rcpf(v); }
__device__ __forceinline__ float exp2_fast(float v){ return __builtin_amdgcn_exp2f(v); }
__device__ __forceinline__ f32x4 mfma16(half8 a, half8 b, f32x4 c){
    return __builtin_amdgcn_mfma_f32_16x16x32_f16(a, b, c, 0, 0, 0);
}

// Block = 16 batches, 16 waves (1024 thr), 256 blocks (1/CU, 4 waves/SIMD).
// Wave w owns ONE A-tile: j in [4w, 4w+4), all 4 gates packed in A rows
// (rr = 4*joff + gate). Lane l holds exactly ONE state (batch=l15, j=4w+l4),
// all 4 gates in its 4 acc regs. 4 waves/SIMD = max latency hiding at
// conserved per-CU issue (trans 224 cyc/SIMD-step, 32 MFMA/CU-step); DS
// b128 doubles vs 8-wave (32/CU-step = ~380 pipe cyc, still < step).
// EW: R14 exp2-form, scalar (1 state/lane), 7 trans + ~12 VALU.
// h stored at slot j directly (identity perm), fp16, XOR-swizzled, dbuf.
// Branch-free t-loop: h-buffer 1 pre-zeroed -> t=0 MFMA reads h(-1)=0.
// D layout: lane l holds D[m=l4*4+r][n=l15] => (batch=l15, j=4w+l4, gate=r).
__global__ __launch_bounds__(1024, 1)
void lstm_mfma_kernel(const float* __restrict__ x,      // [B, T]
                      const float* __restrict__ W_ih,   // [256]
                      const float* __restrict__ W_hh,   // [256, 64]
                      const float* __restrict__ b_ih,   // [256]
                      const float* __restrict__ b_hh,   // [256]
                      const float* __restrict__ fc_W,   // [30, 64]
                      const float* __restrict__ fc_b,   // [30]
                      float* __restrict__ out)          // [B, 30]
{
    __shared__ __align__(16) _Float16 hs[2][16][64];   // h fp16, swizzled, dbuf (4 KB)
    __shared__ float xs[2][64][16];                    // x chunks [buf][t&63][batch] (8 KB)

    const int tid = threadIdx.x;
    const int l   = tid & 63;
    const int w   = tid >> 6;        // 0..15
    const int l15 = l & 15;
    const int l4  = l >> 4;
    const int bb  = blockIdx.x * 16;

    const float L2E  = 1.44269504088896f;
    const float TL2E = 2.88539008177793f;   // 2*log2(e)

    // ---- one-time: A-frag (1 tile), gate-scales folded, identity slot-perm ----
    // lane supplies A[m=l15][k=kc*32+l4*8+e]; row m -> gate=m&3, joff=m>>2
    const int   ga   = l15 & 3;
    const float Srow = (ga == 2) ? TL2E : -L2E;   // tanh rows +2log2e, sigmoid -log2e
    half8 A0, A1;                    // k-chunks 0..31, 32..63
    {
        const int gc = ga*64 + w*4 + (l15 >> 2);   // W_hh row (gate, j_out)
        const float* p = W_hh + gc*64 + l4*8;
        #pragma unroll
        for (int e = 0; e < 8; ++e) {
            A0[e] = (_Float16)(p[e]      * Srow);
            A1[e] = (_Float16)(p[32 + e] * Srow);
        }
    }

    // per-lane x-weight/bias for THE state this lane holds (gate=r, j=jl)
    const int jl = w*4 + l4;
    float wih[4], bia[4];
    #pragma unroll
    for (int r = 0; r < 4; ++r) {
        const float S = (r == 2) ? TL2E : -L2E;
        const int   g = r*64 + jl;
        wih[r] = W_ih[g] * S;
        bia[r] = (b_ih[g] + b_hh[g]) * S;
    }

    // LDS byte offsets: slot j of batch b at (b*128 + j*2) ^ ((b&7)<<4)
    const int rbase = (l15*128 + l4*16) ^ ((l15&7)<<4);   // B-frag kc0; kc1 -> ^64
    const int hwoff = (l15*128 + jl*2)  ^ ((l15&7)<<4);   // b16 write (b=l15, j=jl)
    char* hbase = (char*)hs;

    // stage x chunk 0 (thread (w,l): batch=w, t=l) + ZERO h-buffer 1
    xs[0][l][w] = x[(long long)(bb + w)*T_STEPS + l];
    ((unsigned short*)hs)[1024 + tid] = 0;   // buf1 = fp16[1024..2048) -> h(-1)=0
    __syncthreads();

    float cc = 0.f, hh = 0.f;
    float xv = xs[0][0][l15];

    for (int t = 0; t < T_STEPS; ++t) {
        // B-frag reads first (longest-latency consumer chain)
        const char* hp = hbase + ((t + 1) & 1) * 2048;
        const half8 b0 = *(const half8*)(hp + rbase);
        const half8 b1 = *(const half8*)(hp + (rbase ^ 64));

        if ((t & 63) == 0 && t + 64 < T_STEPS)   // stage next x chunk
            xs[(((t >> 6) & 1)) ^ 1][l][w] =
                x[(long long)(bb + w)*T_STEPS + t + 64 + l];

        // serial 2-MFMA chain (C-init carries x*W_ih + bias)
        f32x4 acc;
        #pragma unroll
        for (int r = 0; r < 4; ++r) acc[r] = fmaf(xv, wih[r], bia[r]);
        acc = mfma16(A0, b0, acc);
        acc = mfma16(A1, b1, acc);

        // prefetch next x (chunk staged >=1 barrier ago)
        const int t1 = (t + 1 < T_STEPS) ? t + 1 : t;
        const float xvn = xs[(t1 >> 6) & 1][t1 & 63][l15];

        // scalar elementwise (R14 form), 7 trans + ~12 VALU:
        const float eI = exp2_fast(acc[0]);
        const float eF = exp2_fast(acc[1]);
        const float eG = exp2_fast(acc[2]);
        const float eO = exp2_fast(acc[3]);
        const float u  = 1.0f + eI;
        const float v  = 1.0f + eF;
        const float s  = 1.0f + eG;
        const float m  = s - 2.0f;
        const float us = u * s;
        const float N  = fmaf(cc, us, v * m);
        cc = N * rcp_fast(us * v);                     // true cell state
        const float a2 = fminf(cc * TL2E, 80.0f);
        const float Tt = exp2_fast(a2);
        const float Dh = (1.0f + eO) * (Tt + 1.0f);
        hh = (Tt - 1.0f) * rcp_fast(Dh);               // h = o * tanh(c)

        *(_Float16*)(hbase + (t & 1)*2048 + hwoff) = (_Float16)hh;
        xv = xvn;
        __syncthreads();   // h(t) visible for step t+1
    }

    // ---- fused FC head ----
    float* hsc = (float*)xs;            // reuse: hsc[16][64]
    hsc[l15*64 + jl] = hh;              // bijective (batch=l15, j=jl)
    __syncthreads();

    if (tid < 16*FORECAST) {
        const int b = tid / FORECAST;
        const int f = tid % FORECAST;
        float a = fc_b[f];
        #pragma unroll
        for (int jj = 0; jj < 64; ++jj)
            a = fmaf(hsc[b*64 + jj], fc_W[f*64 + jj], a);
        out[(long long)(bb + b)*FORECAST + f] = a;
    }
}

extern "C" void kernel_launch(void* const* d_in, const int* in_sizes, int n_in,
                              void* d_out, int out_size, void* d_ws, size_t ws_size,
                              hipStream_t stream) {
    const float* x    = (const float*)d_in[0];
    const float* W_ih = (const float*)d_in[1];
    const float* W_hh = (const float*)d_in[2];
    const float* b_ih = (const float*)d_in[3];
    const float* b_hh = (const float*)d_in[4];
    const float* fc_W = (const float*)d_in[5];
    const float* fc_b = (const float*)d_in[6];
    float* out = (float*)d_out;

    // 4096 / 16 batches per block = 256 blocks (1/CU), 16 waves = 4/SIMD
    lstm_mfma_kernel<<<256, 1024, 0, stream>>>(x, W_ih, W_hh, b_ih, b_hh, fc_W, fc_b, out);
}

// Round 16
// 371.086 us; speedup vs baseline: 1.1598x; 1.1598x over previous
//
#include <hip/hip_runtime.h>
#include <math.h>

#define T_STEPS 1024
#define FORECAST 30

typedef __attribute__((ext_vector_type(8))) _Float16 half8;    // 8 fp16 = 4 VGPRs
typedef __attribute__((ext_vector_type(2))) _Float16 half2v;   // 2 fp16 = 1 VGPR
typedef __attribute__((ext_vector_type(4))) float f32x4;
typedef __attribute__((ext_vector_type(2))) float f32x2;       // -> v_pk_*_f32

__device__ __forceinline__ float rcp_fast(float v){ return __builtin_amdgcn_rcpf(v); }
__device__ __forceinline__ float exp2_fast(float v){ return __builtin_amdgcn_exp2f(v); }
__device__ __forceinline__ f32x4 mfma16(half8 a, half8 b, f32x4 c){
    return __builtin_amdgcn_mfma_f32_16x16x32_f16(a, b, c, 0, 0, 0);
}
__device__ __forceinline__ half2v pack_f16(float a, float b){
    return __builtin_bit_cast(half2v, __builtin_amdgcn_cvt_pkrtz(a, b));  // v_cvt_pkrtz_f16_f32
}

// R14 structure (measured optimum of the wave-count matrix: 1/SIMD=450us,
// 2/SIMD=394us, 4/SIMD=430-477us) + 2-step unroll so h-buffer indices are
// compile-time and the staging branch runs once per pair.
// Block = 16 batches, 8 waves (512 thr), 256 blocks (1/CU, 2 waves/SIMD).
// Wave w owns j in [8w,8w+8) as TWO A-tiles sharing B-frags (2 ds_read_b128).
// EW (per 2 states, f32x2-packed -> v_pk_*): i=1/u, f=1/v, g=(s-2)/s,
// o=1/(1+eO); c' = (c*us + v*m)/(us*v); h = (Tt-1)/((1+eO)(Tt+1)),
// Tt = 2^min(c'*2log2e, 80).  14 trans + ~17 pk-VALU / wave-step.
// h slot p = w*8+l4*2+T <-> j=(p&~7)+(p&1)*4+((p&7)>>1) (perm baked into A).
// D layout: lane l holds D[m=l4*4+r][n=l15] => (batch=l15, j, gate=r) in-lane.
// Branch-free t=0: h-buffer 1 pre-zeroed -> first MFMA reads h(-1)=0.
__global__ __launch_bounds__(512, 1)
void lstm_mfma_kernel(const float* __restrict__ x,      // [B, T]
                      const float* __restrict__ W_ih,   // [256]
                      const float* __restrict__ W_hh,   // [256, 64]
                      const float* __restrict__ b_ih,   // [256]
                      const float* __restrict__ b_hh,   // [256]
                      const float* __restrict__ fc_W,   // [30, 64]
                      const float* __restrict__ fc_b,   // [30]
                      float* __restrict__ out)          // [B, 30]
{
    __shared__ __align__(16) _Float16 hs[2][16][64];   // h fp16, swizzled slots, dbuf
    __shared__ float xs[2][64][16];                    // x chunks [buf][t&63][batch]

    const int tid = threadIdx.x;
    const int l   = tid & 63;
    const int w   = tid >> 6;        // 0..7
    const int l15 = l & 15;
    const int l4  = l >> 4;
    const int bb  = blockIdx.x * 16;

    const float L2E  = 1.44269504088896f;
    const float TL2E = 2.88539008177793f;   // 2*log2(e)

    // ---- one-time: A-frags (2 tiles), gate-scales folded, j-perm baked ----
    const int   ga   = l15 & 3;
    const float Srow = (ga == 2) ? TL2E : -L2E;   // tanh rows +2log2e, sigmoid -log2e
    half8 A[2][2];                   // [tile][k-chunk]
    #pragma unroll
    for (int T = 0; T < 2; ++T) {
        const int gc = ga*64 + w*8 + T*4 + (l15 >> 2);   // W_hh row (gate, j_out)
        #pragma unroll
        for (int kc = 0; kc < 2; ++kc) {
            #pragma unroll
            for (int e = 0; e < 8; ++e) {
                const int p   = kc*32 + l4*8 + e;        // B slot
                const int jin = (p & ~7) + ((p & 1) << 2) + ((p & 7) >> 1);
                A[T][kc][e] = (_Float16)(W_hh[gc*64 + jin] * Srow);
            }
        }
    }

    // per-lane x-weights/bias for the 2 states this lane HOLDS (gate=r, j=jT)
    float wih[2][4], bia[2][4];
    #pragma unroll
    for (int T = 0; T < 2; ++T) {
        const int jT = w*8 + T*4 + l4;
        #pragma unroll
        for (int r = 0; r < 4; ++r) {
            const float S = (r == 2) ? TL2E : -L2E;
            const int   g = r*64 + jT;
            wih[T][r] = W_ih[g] * S;
            bia[T][r] = (b_ih[g] + b_hh[g]) * S;
        }
    }

    // LDS byte offsets (swizzle ^((b&7)<<4)):
    const int rbase = (l15*128 + l4*16) ^ ((l15&7)<<4);           // B-frag kc0; kc1 -> ^64
    const int hwoff = (l15*128 + w*16 + l4*4) ^ ((l15&7)<<4);     // b32 write, slots p0,p0+1
    char* const buf0 = (char*)hs;
    char* const buf1 = (char*)hs + 2048;

    // stage x chunk 0 + ZERO h-buffer 1 (first MFMA reads h(-1)=0)
    #pragma unroll
    for (int it = 0; it < 2; ++it) {
        const int b = w*2 + it;
        xs[0][l][b] = x[(long long)(bb + b)*T_STEPS + l];
    }
    ((unsigned*)hs)[512 + tid] = 0u;     // buf1 = bytes [2048,4096)
    __syncthreads();

    f32x2 cc = {0.f, 0.f}, hh01 = {0.f, 0.f};
    float xv = xs[0][0][l15];

    #define LSTM_STEP(T_CUR, RBUF, WBUF)                                        \
    {                                                                           \
        const int t_ = (T_CUR);                                                 \
        const half8 b0 = *(const half8*)((RBUF) + rbase);                       \
        const half8 b1 = *(const half8*)((RBUF) + (rbase ^ 64));                \
        f32x4 acc0, acc1;                                                       \
        _Pragma("unroll")                                                       \
        for (int r = 0; r < 4; ++r) {                                           \
            acc0[r] = fmaf(xv, wih[0][r], bia[0][r]);                           \
            acc1[r] = fmaf(xv, wih[1][r], bia[1][r]);                           \
        }                                                                       \
        acc0 = mfma16(A[0][0], b0, acc0);                                       \
        acc1 = mfma16(A[1][0], b0, acc1);                                       \
        acc0 = mfma16(A[0][1], b1, acc0);                                       \
        acc1 = mfma16(A[1][1], b1, acc1);                                       \
        const int t1_ = t_ + 1;                                                 \
        const float xvn = xs[(t1_ >> 6) & 1][t1_ & 63][l15];                    \
        f32x2 eI, eF, eG, eO;                                                   \
        eI[0] = exp2_fast(acc0[0]); eI[1] = exp2_fast(acc1[0]);                 \
        eF[0] = exp2_fast(acc0[1]); eF[1] = exp2_fast(acc1[1]);                 \
        eG[0] = exp2_fast(acc0[2]); eG[1] = exp2_fast(acc1[2]);                 \
        eO[0] = exp2_fast(acc0[3]); eO[1] = exp2_fast(acc1[3]);                 \
        const f32x2 u  = eI + 1.0f;                                             \
        const f32x2 v  = eF + 1.0f;                                             \
        const f32x2 s  = eG + 1.0f;                                             \
        const f32x2 m  = s - 2.0f;                                              \
        const f32x2 us = u * s;                                                 \
        const f32x2 vm = v * m;                                                 \
        const f32x2 N  = cc * us + vm;                                          \
        const f32x2 Dd = us * v;                                                \
        f32x2 rD; rD[0] = rcp_fast(Dd[0]); rD[1] = rcp_fast(Dd[1]);             \
        cc = N * rD;                                                            \
        f32x2 a2 = cc * TL2E;                                                   \
        a2[0] = fminf(a2[0], 80.f); a2[1] = fminf(a2[1], 80.f);                 \
        const f32x2 oD = eO + 1.0f;                                             \
        f32x2 Tt; Tt[0] = exp2_fast(a2[0]); Tt[1] = exp2_fast(a2[1]);           \
        const f32x2 Dh = oD * (Tt + 1.0f);                                      \
        f32x2 rH; rH[0] = rcp_fast(Dh[0]); rH[1] = rcp_fast(Dh[1]);             \
        hh01 = (Tt - 1.0f) * rH;                                                \
        *(half2v*)((WBUF) + hwoff) = pack_f16(hh01[0], hh01[1]);                \
        xv = xvn;                                                               \
        __syncthreads();                                                        \
    }

    for (int t2 = 0; t2 < T_STEPS; t2 += 2) {
        if ((t2 & 63) == 0 && t2 + 64 < T_STEPS) {   // stage next x chunk (pair-aligned)
            #pragma unroll
            for (int it = 0; it < 2; ++it) {
                const int b = w*2 + it;
                xs[(((t2 >> 6) & 1)) ^ 1][l][b] =
                    x[(long long)(bb + b)*T_STEPS + t2 + 64 + l];
            }
        }
        LSTM_STEP(t2,     buf1, buf0);   // even t: read h(t-1) from buf1, write buf0
        LSTM_STEP(t2 + 1, buf0, buf1);   // odd  t: read from buf0, write buf1
    }
    #undef LSTM_STEP

    // ---- fused FC head ----
    float* hsc = (float*)xs;            // reuse: hsc[16][64], real-j indexing
    hsc[l15*64 + w*8 + l4]     = hh01[0];
    hsc[l15*64 + w*8 + 4 + l4] = hh01[1];
    __syncthreads();

    if (tid < 16*FORECAST) {
        const int b = tid / FORECAST;
        const int f = tid % FORECAST;
        float a = fc_b[f];
        #pragma unroll
        for (int jj = 0; jj < 64; ++jj)
            a = fmaf(hsc[b*64 + jj], fc_W[f*64 + jj], a);
        out[(long long)(bb + b)*FORECAST + f] = a;
    }
}

extern "C" void kernel_launch(void* const* d_in, const int* in_sizes, int n_in,
                              void* d_out, int out_size, void* d_ws, size_t ws_size,
                              hipStream_t stream) {
    const float* x    = (const float*)d_in[0];
    const float* W_ih = (const float*)d_in[1];
    const float* W_hh = (const float*)d_in[2];
    const float* b_ih = (const float*)d_in[3];
    const float* b_hh = (const float*)d_in[4];
    const float* fc_W = (const float*)d_in[5];
    const float* fc_b = (const float*)d_in[6];
    float* out = (float*)d_out;

    // 4096 / 16 batches per block = 256 blocks (1 per CU), 8 waves (2/SIMD)
    lstm_mfma_kernel<<<256, 512, 0, stream>>>(x, W_ih, W_hh, b_ih, b_hh, fc_W, fc_b, out);
}

// Round 17
// 367.596 us; speedup vs baseline: 1.1708x; 1.0095x over previous
//
#include <hip/hip_runtime.h>
#include <math.h>

#define T_STEPS 1024
#define FORECAST 30

typedef __attribute__((ext_vector_type(8))) _Float16 half8;    // 8 fp16 = 4 VGPRs
typedef __attribute__((ext_vector_type(2))) _Float16 half2v;   // 2 fp16 = 1 VGPR
typedef __attribute__((ext_vector_type(4))) float f32x4;
typedef __attribute__((ext_vector_type(2))) float f32x2;       // -> v_pk_*_f32

__device__ __forceinline__ float rcp_fast(float v){ return __builtin_amdgcn_rcpf(v); }
__device__ __forceinline__ float exp2_fast(float v){ return __builtin_amdgcn_exp2f(v); }
__device__ __forceinline__ float med3(float a, float lo, float hi){ return __builtin_amdgcn_fmed3f(a, lo, hi); }
__device__ __forceinline__ f32x4 mfma16(half8 a, half8 b, f32x4 c){
    return __builtin_amdgcn_mfma_f32_16x16x32_f16(a, b, c, 0, 0, 0);
}
__device__ __forceinline__ half2v pack_f16(float a, float b){
    return __builtin_bit_cast(half2v, __builtin_amdgcn_cvt_pkrtz(a, b));  // v_cvt_pkrtz_f16_f32
}

// R16 skeleton (measured optimum: 8 waves/block, 2/SIMD, 2-step unroll) with
// the EW chain shortened by ONE trans stage via [7/6] Pade tanh (clean test
// of R13's idea without its split-accumulator confound):
//   chain: exp2(gates) -> rcp(cell) -> VALU poly -> rcp(h)   [3 trans stages]
//   i=1/u, f=1/v, g=(s-2)/s, o=1/(1+eO); c' = (c*us + v*m)/(us*v)
//   tanh(ct) ~= ct(10395+1260z+21z^2)/(10395+4725z+210z^2+z^3), ct=clamp(c',4.6)
//   h = Pn * rcp((1+eO) * Pden)      (o-gate rcp merged, R13-validated numerics)
// Block = 16 batches, 8 waves (512 thr), 256 blocks (1/CU, 2 waves/SIMD).
// Wave w owns j in [8w,8w+8) as TWO A-tiles sharing B-frags (2 ds_read_b128).
// h slot p = w*8+l4*2+T <-> j=(p&~7)+(p&1)*4+((p&7)>>1) (perm baked into A).
// D layout: lane l holds D[m=l4*4+r][n=l15] => (batch=l15, j, gate=r) in-lane.
// Branch-free t=0: h-buffer 1 pre-zeroed -> first MFMA reads h(-1)=0.
__global__ __launch_bounds__(512, 1)
void lstm_mfma_kernel(const float* __restrict__ x,      // [B, T]
                      const float* __restrict__ W_ih,   // [256]
                      const float* __restrict__ W_hh,   // [256, 64]
                      const float* __restrict__ b_ih,   // [256]
                      const float* __restrict__ b_hh,   // [256]
                      const float* __restrict__ fc_W,   // [30, 64]
                      const float* __restrict__ fc_b,   // [30]
                      float* __restrict__ out)          // [B, 30]
{
    __shared__ __align__(16) _Float16 hs[2][16][64];   // h fp16, swizzled slots, dbuf
    __shared__ float xs[2][64][16];                    // x chunks [buf][t&63][batch]

    const int tid = threadIdx.x;
    const int l   = tid & 63;
    const int w   = tid >> 6;        // 0..7
    const int l15 = l & 15;
    const int l4  = l >> 4;
    const int bb  = blockIdx.x * 16;

    const float L2E  = 1.44269504088896f;
    const float TL2E = 2.88539008177793f;   // 2*log2(e)

    // ---- one-time: A-frags (2 tiles), gate-scales folded, j-perm baked ----
    const int   ga   = l15 & 3;
    const float Srow = (ga == 2) ? TL2E : -L2E;   // tanh rows +2log2e, sigmoid -log2e
    half8 A[2][2];                   // [tile][k-chunk]
    #pragma unroll
    for (int T = 0; T < 2; ++T) {
        const int gc = ga*64 + w*8 + T*4 + (l15 >> 2);   // W_hh row (gate, j_out)
        #pragma unroll
        for (int kc = 0; kc < 2; ++kc) {
            #pragma unroll
            for (int e = 0; e < 8; ++e) {
                const int p   = kc*32 + l4*8 + e;        // B slot
                const int jin = (p & ~7) + ((p & 1) << 2) + ((p & 7) >> 1);
                A[T][kc][e] = (_Float16)(W_hh[gc*64 + jin] * Srow);
            }
        }
    }

    // per-lane x-weights/bias for the 2 states this lane HOLDS (gate=r, j=jT)
    float wih[2][4], bia[2][4];
    #pragma unroll
    for (int T = 0; T < 2; ++T) {
        const int jT = w*8 + T*4 + l4;
        #pragma unroll
        for (int r = 0; r < 4; ++r) {
            const float S = (r == 2) ? TL2E : -L2E;
            const int   g = r*64 + jT;
            wih[T][r] = W_ih[g] * S;
            bia[T][r] = (b_ih[g] + b_hh[g]) * S;
        }
    }

    // LDS byte offsets (swizzle ^((b&7)<<4)):
    const int rbase = (l15*128 + l4*16) ^ ((l15&7)<<4);           // B-frag kc0; kc1 -> ^64
    const int hwoff = (l15*128 + w*16 + l4*4) ^ ((l15&7)<<4);     // b32 write, slots p0,p0+1
    char* const buf0 = (char*)hs;
    char* const buf1 = (char*)hs + 2048;

    // stage x chunk 0 + ZERO h-buffer 1 (first MFMA reads h(-1)=0)
    #pragma unroll
    for (int it = 0; it < 2; ++it) {
        const int b = w*2 + it;
        xs[0][l][b] = x[(long long)(bb + b)*T_STEPS + l];
    }
    ((unsigned*)hs)[512 + tid] = 0u;     // buf1 = bytes [2048,4096)
    __syncthreads();

    f32x2 cc = {0.f, 0.f}, hh01 = {0.f, 0.f};
    float xv = xs[0][0][l15];

    #define LSTM_STEP(T_CUR, RBUF, WBUF)                                        \
    {                                                                           \
        const int t_ = (T_CUR);                                                 \
        const half8 b0 = *(const half8*)((RBUF) + rbase);                       \
        const half8 b1 = *(const half8*)((RBUF) + (rbase ^ 64));                \
        f32x4 acc0, acc1;                                                       \
        _Pragma("unroll")                                                       \
        for (int r = 0; r < 4; ++r) {                                           \
            acc0[r] = fmaf(xv, wih[0][r], bia[0][r]);                           \
            acc1[r] = fmaf(xv, wih[1][r], bia[1][r]);                           \
        }                                                                       \
        acc0 = mfma16(A[0][0], b0, acc0);                                       \
        acc1 = mfma16(A[1][0], b0, acc1);                                       \
        acc0 = mfma16(A[0][1], b1, acc0);                                       \
        acc1 = mfma16(A[1][1], b1, acc1);                                       \
        const int t1_ = t_ + 1;                                                 \
        const float xvn = xs[(t1_ >> 6) & 1][t1_ & 63][l15];                    \
        f32x2 eI, eF, eG, eO;                                                   \
        eI[0] = exp2_fast(acc0[0]); eI[1] = exp2_fast(acc1[0]);                 \
        eF[0] = exp2_fast(acc0[1]); eF[1] = exp2_fast(acc1[1]);                 \
        eG[0] = exp2_fast(acc0[2]); eG[1] = exp2_fast(acc1[2]);                 \
        eO[0] = exp2_fast(acc0[3]); eO[1] = exp2_fast(acc1[3]);                 \
        const f32x2 u  = eI + 1.0f;                                             \
        const f32x2 v  = eF + 1.0f;                                             \
        const f32x2 s  = eG + 1.0f;                                             \
        const f32x2 m  = s - 2.0f;                                              \
        const f32x2 us = u * s;                                                 \
        const f32x2 vm = v * m;                                                 \
        const f32x2 N  = cc * us + vm;                                          \
        const f32x2 Dd = us * v;                                                \
        f32x2 rD; rD[0] = rcp_fast(Dd[0]); rD[1] = rcp_fast(Dd[1]);             \
        cc = N * rD;                                   /* true cell state */    \
        f32x2 ct;                                                               \
        ct[0] = med3(cc[0], -4.6f, 4.6f);                                       \
        ct[1] = med3(cc[1], -4.6f, 4.6f);                                       \
        const f32x2 z = ct * ct;                                                \
        f32x2 q = z * 21.0f + 1260.0f;                                          \
        q = z * q + 10395.0f;                                                   \
        const f32x2 Pn = ct * q;                                                \
        f32x2 r_ = z + 210.0f;                                                  \
        r_ = z * r_ + 4725.0f;                                                  \
        r_ = z * r_ + 10395.0f;                                                 \
        const f32x2 Dh = (eO + 1.0f) * r_;             /* merge o-gate rcp */   \
        f32x2 rH; rH[0] = rcp_fast(Dh[0]); rH[1] = rcp_fast(Dh[1]);             \
        hh01 = Pn * rH;                                /* h = o * tanh(c) */    \
        *(half2v*)((WBUF) + hwoff) = pack_f16(hh01[0], hh01[1]);                \
        xv = xvn;                                                               \
        __syncthreads();                                                        \
    }

    for (int t2 = 0; t2 < T_STEPS; t2 += 2) {
        if ((t2 & 63) == 0 && t2 + 64 < T_STEPS) {   // stage next x chunk (pair-aligned)
            #pragma unroll
            for (int it = 0; it < 2; ++it) {
                const int b = w*2 + it;
                xs[(((t2 >> 6) & 1)) ^ 1][l][b] =
                    x[(long long)(bb + b)*T_STEPS + t2 + 64 + l];
            }
        }
        LSTM_STEP(t2,     buf1, buf0);   // even t: read h(t-1) from buf1, write buf0
        LSTM_STEP(t2 + 1, buf0, buf1);   // odd  t: read from buf0, write buf1
    }
    #undef LSTM_STEP

    // ---- fused FC head ----
    float* hsc = (float*)xs;            // reuse: hsc[16][64], real-j indexing
    hsc[l15*64 + w*8 + l4]     = hh01[0];
    hsc[l15*64 + w*8 + 4 + l4] = hh01[1];
    __syncthreads();

    if (tid < 16*FORECAST) {
        const int b = tid / FORECAST;
        const int f = tid % FORECAST;
        float a = fc_b[f];
        #pragma unroll
        for (int jj = 0; jj < 64; ++jj)
            a = fmaf(hsc[b*64 + jj], fc_W[f*64 + jj], a);
        out[(long long)(bb + b)*FORECAST + f] = a;
    }
}

extern "C" void kernel_launch(void* const* d_in, const int* in_sizes, int n_in,
                              void* d_out, int out_size, void* d_ws, size_t ws_size,
                              hipStream_t stream) {
    const float* x    = (const float*)d_in[0];
    const float* W_ih = (const float*)d_in[1];
    const float* W_hh = (const float*)d_in[2];
    const float* b_ih = (const float*)d_in[3];
    const float* b_hh = (const float*)d_in[4];
    const float* fc_W = (const float*)d_in[5];
    const float* fc_b = (const float*)d_in[6];
    float* out = (float*)d_out;

    // 4096 / 16 batches per block = 256 blocks (1 per CU), 8 waves (2/SIMD)
    lstm_mfma_kernel<<<256, 512, 0, stream>>>(x, W_ih, W_hh, b_ih, b_hh, fc_W, fc_b, out);
}